// Round 1
// 1710.465 us; speedup vs baseline: 6.6064x; 6.6064x over previous
//
#include <hip/hip_runtime.h>
#include <hip/hip_bf16.h>
#include <math.h>

#define N_NODES 50000
#define E1 300000
#define EN 30000
#define ETOT 330000

typedef __hip_bfloat16 bf16;

__device__ __forceinline__ float b2f(bf16 x){ return __bfloat162float(x); }
__device__ __forceinline__ bf16 f2b(float x){ return __float2bfloat16(x); }

// dual-dtype load/store: f32==true -> buffer is float32, else bf16
__device__ __forceinline__ float ldf(const void* p, long i, bool f32){
  return f32 ? ((const float*)p)[i] : b2f(((const bf16*)p)[i]);
}
__device__ __forceinline__ void stf(void* p, long i, float v, bool f32){
  if (f32) ((float*)p)[i] = v; else ((bf16*)p)[i] = f2b(v);
}

template<int NT>
__device__ __forceinline__ float block_sum(float v){
  __shared__ float sm[NT/64];
  #pragma unroll
  for (int o=32;o>0;o>>=1) v += __shfl_down(v,o);
  if ((threadIdx.x & 63)==0) sm[threadIdx.x>>6] = v;
  __syncthreads();
  float t = 0.f;
  #pragma unroll
  for (int w=0;w<NT/64;w++) t += sm[w];
  __syncthreads();
  return t;
}

// Detect input dtype (proven in R4): flag=0 -> bf16, flag=1 -> fp32
__global__ void k_detect(const void* __restrict__ emb, int* __restrict__ flag){
  const unsigned short* h = (const unsigned short*)emb;
  int sane = 0;
  for (int i=0;i<128;i++){
    unsigned e = (h[i]>>7)&0xFFu;
    if (e>=112u && e<=143u) sane++;
  }
  *flag = (sane >= 112) ? 0 : 1;
}

// NEW: xnorm = l2norm(emb) rows, fp32 (computed ONCE, shared by both heads)
__global__ void k_norm(const void* __restrict__ emb, const int* __restrict__ flag,
                       float* __restrict__ xn){
  bool f32 = flag[0] != 0;
  int n = blockIdx.x, j = threadIdx.x;   // 128 threads
  float v = ldf(emb, (long)n*128 + j, f32);
  float nrm = fmaxf(sqrtf(block_sum<128>(v*v)), 1e-12f);
  xn[(long)n*128 + j] = v / nrm;
}

// Layer-1 relation projection: rp[t] fp32, sr[t]
__global__ void k_rproj1(const void* __restrict__ rel, const void* __restrict__ a,
                         const void* __restrict__ a2, const int* __restrict__ flag,
                         float* __restrict__ rp, float* __restrict__ sr){
  bool f32 = flag[0] != 0;
  int t = blockIdx.x, j = threadIdx.x;   // 128 threads
  __shared__ float rs_[128];
  rs_[j] = ldf(rel, (long)t*128 + j, f32);
  __syncthreads();
  long ar = (long)j*384 + 256;
  float acc = 0.f;
  #pragma unroll 4
  for (int k=0;k<128;k++) acc += rs_[k]*ldf(a, ar+k, f32);
  rp[(long)t*128+j] = acc;
  float v = block_sum<128>(acc*ldf(a2, j, f32));
  if (j==0) sr[t] = v;
}

__global__ void k_rproj1b(const void* __restrict__ rel, const void* __restrict__ a,
                          const void* __restrict__ a2, const int* __restrict__ flag,
                          long abias, long a2bias,
                          float* __restrict__ rp, float* __restrict__ sr){
  bool f32 = flag[0] != 0;
  int t = blockIdx.x, j = threadIdx.x;
  __shared__ float rs_[128];
  rs_[j] = ldf(rel, (long)t*128 + j, f32);
  __syncthreads();
  long ar = abias + (long)j*384 + 256;
  float acc = 0.f;
  #pragma unroll 4
  for (int k=0;k<128;k++) acc += rs_[k]*ldf(a, ar+k, f32);
  rp[(long)t*128+j] = acc;
  float v = block_sum<128>(acc*ldf(a2, a2bias + j, f32));
  if (j==0) sr[t] = v;
}

// Edge scatter: one wave/edge. w=exp(-lrelu(score)); scat[dst] += w*(ps[src]+rp[type])
template<int D>
__global__ void k_edge(const int* __restrict__ el, const int* __restrict__ et,
                       const int* __restrict__ eln, const int* __restrict__ etn,
                       const float* __restrict__ ps, const float* __restrict__ rp,
                       const float* __restrict__ sd, const float* __restrict__ ss,
                       const float* __restrict__ sr,
                       float* __restrict__ scat, float* __restrict__ rowsum){
  long gid = (long)blockIdx.x*blockDim.x + threadIdx.x;
  long wid = gid >> 6;
  int lane = threadIdx.x & 63;
  if (wid >= ETOT) return;
  int dst, src; const float *pr1, *pr2 = nullptr; float srv;
  if (wid < E1){
    int e = (int)wid;
    dst = el[e]; src = el[E1 + e];
    int t = et[e]; pr1 = rp + (long)t*D; srv = sr[t];
  } else {
    int e = (int)wid - E1;
    dst = eln[e]; src = eln[EN + e];
    int t0 = etn[2*e], t1 = etn[2*e+1];
    pr1 = rp + (long)t0*D; pr2 = rp + (long)t1*D; srv = sr[t0] + sr[t1];
  }
  float score = sd[dst] + ss[src] + srv;
  float lr = score > 0.f ? score : 0.2f*score;
  float w = expf(-lr);
  if (lane == 0) atomicAdd(rowsum + dst, w);
  const float* psr = ps + (long)src*D;
  float* outp = scat + (long)dst*D;
  if (pr2){
    #pragma unroll
    for (int j=lane; j<D; j+=64) atomicAdd(outp+j, w*(psr[j] + pr1[j] + pr2[j]));
  } else {
    #pragma unroll
    for (int j=lane; j<D; j+=64) atomicAdd(outp+j, w*(psr[j] + pr1[j]));
  }
}

// Layer-1 finalize: x[:, hoff+j] = elu((rs*pd + scat)/denom), fp32
__global__ void k_fin1(const float* __restrict__ pd, const float* __restrict__ scat,
                       const float* __restrict__ rowsum, float* __restrict__ x, int hoff){
  int n = blockIdx.x, j = threadIdx.x;   // 128 threads
  float rs = rowsum[n];
  float denom = (rs == 0.f) ? 1e-12f : rs;
  float hr = rs*pd[(long)n*128+j] + scat[(long)n*128+j];
  float hv = hr/denom;
  hv = hv > 0.f ? hv : (expf(hv) - 1.f);
  x[(long)n*256 + hoff + j] = hv;
}

// out_relation_1 = rel @ W  (fp32 copy to ws + dual-dtype output at element offset)
__global__ void k_rel2(const void* __restrict__ rel, const void* __restrict__ W,
                       const int* __restrict__ flag,
                       float* __restrict__ r2, void* __restrict__ out){
  bool f32 = flag[0] != 0;
  int t = blockIdx.x, j = threadIdx.x;   // 256 threads
  __shared__ float rs_[128];
  if (j < 128) rs_[j] = ldf(rel, (long)t*128 + j, f32);
  __syncthreads();
  float acc = 0.f;
  #pragma unroll 4
  for (int k=0;k<128;k++) acc += rs_[k]*ldf(W, (long)k*256 + j, f32);
  r2[(long)t*256+j] = acc;
  stf(out, 12800000L + (long)t*256 + j, acc, f32);
}

// Layer-2 relation projection: rp2 fp32, sr2
__global__ void k_rproj2(const float* __restrict__ r2, const void* __restrict__ a,
                         const void* __restrict__ a2, const int* __restrict__ flag,
                         float* __restrict__ rp, float* __restrict__ sr){
  bool f32 = flag[0] != 0;
  int t = blockIdx.x, j = threadIdx.x;   // 256 threads
  __shared__ float rs_[256];
  rs_[j] = r2[(long)t*256 + j];
  __syncthreads();
  long ar = (long)j*768 + 512;
  float acc = 0.f;
  #pragma unroll 4
  for (int k=0;k<256;k++) acc += rs_[k]*ldf(a, ar+k, f32);
  rp[(long)t*256+j] = acc;
  float v = block_sum<256>(acc*ldf(a2, j, f32));
  if (j==0) sr[t] = v;
}

// Transpose weight block to fp32 [k][J]: dst[k*J+j] = src[bias + j*jstride + k]
__global__ void k_trF(const void* __restrict__ src, const int* __restrict__ flag,
                      long bias, long jstride, int J, float* __restrict__ dst){
  bool f32 = flag[0] != 0;
  int k = blockIdx.x, j = threadIdx.x;
  dst[(long)k*J + j] = ldf(src, bias + (long)j*jstride + k, f32);
}

// Dual projection, coalesced: O1[n*ldc+t] = sum_k X[n*K+k]*WT1[k*NT+t]; O2 likewise.
template<int NT, int K, int BM>
__global__ __launch_bounds__(NT) void k_projT(
    const float* __restrict__ X, int N,
    const float* __restrict__ WT1, const float* __restrict__ WT2,
    float* __restrict__ O1, float* __restrict__ O2, int ldc){
  __shared__ float xs[BM][K];
  int t = threadIdx.x;
  int n0 = blockIdx.x * BM;
  for (int idx = t; idx < BM*K; idx += NT){
    int m = idx / K, k = idx % K;
    int n = n0 + m;
    xs[m][k] = (n < N) ? X[(long)n*K + k] : 0.f;
  }
  __syncthreads();
  float a1c[BM], a2c[BM];
  #pragma unroll
  for (int m=0;m<BM;m++){ a1c[m]=0.f; a2c[m]=0.f; }
  #pragma unroll 4
  for (int k=0;k<K;k++){
    float w1 = WT1[(long)k*NT + t];
    float w2 = WT2[(long)k*NT + t];
    #pragma unroll
    for (int m=0;m<BM;m++){
      a1c[m] += xs[m][k]*w1;
      a2c[m] += xs[m][k]*w2;
    }
  }
  #pragma unroll
  for (int m=0;m<BM;m++){
    int n = n0 + m;
    if (n < N){
      O1[(long)n*ldc + t] = a1c[m];
      O2[(long)n*ldc + t] = a2c[m];
    }
  }
}

// s1[n]=dot(P[n,:],a2), s2[n]=dot(Q[n,:],a2)  (dual-dtype a2)
template<int D>
__global__ void k_scoreF(const float* __restrict__ P, const float* __restrict__ Q,
                         const void* __restrict__ a2, long bias,
                         const int* __restrict__ flag,
                         float* __restrict__ s1, float* __restrict__ s2){
  bool f32 = flag[0] != 0;
  int n = blockIdx.x, j = threadIdx.x;
  float a2j = ldf(a2, bias + j, f32);
  float v1 = block_sum<D>(P[(long)n*D+j]*a2j);
  float v2 = block_sum<D>(Q[(long)n*D+j]*a2j);
  if (j==0){ s1[n] = v1; s2[n] = v2; }
}

__global__ void k_mask(const int* __restrict__ bi, float* __restrict__ mask){
  int i = blockIdx.x*blockDim.x + threadIdx.x;
  if (i < 4096) mask[bi[i*3 + 2]] = 1.f;
}

// entities_upgraded = l2norm(emb) @ W_entities -> eu fp32
__global__ void k_entup(const void* __restrict__ emb, const void* __restrict__ We,
                        const int* __restrict__ flag, float* __restrict__ eu){
  bool f32 = flag[0] != 0;
  int n = blockIdx.x, j = threadIdx.x;   // 256 threads
  __shared__ float es[128];
  float v = (j < 128) ? ldf(emb, (long)n*128 + j, f32) : 0.f;
  float nrm = fmaxf(sqrtf(block_sum<256>(v*v)), 1e-12f);
  if (j < 128) es[j] = v / nrm;
  __syncthreads();
  float acc = 0.f;
  #pragma unroll 4
  for (int k=0;k<128;k++) acc += es[k]*ldf(We, (long)k*256 + j, f32);
  eu[(long)n*256+j] = acc;
}

// Final: out0 = l2norm(eu + mask*elu(hraw/denom)), out2 = l2norm(elu(hraw))
__global__ void k_final(const float* __restrict__ p2d, const float* __restrict__ scat2,
                        const float* __restrict__ rowsum2, const float* __restrict__ eu,
                        const float* __restrict__ mask, const int* __restrict__ flag,
                        void* __restrict__ out){
  bool f32 = flag[0] != 0;
  int n = blockIdx.x, j = threadIdx.x;   // 256 threads
  float rs = rowsum2[n];
  float denom = (rs == 0.f) ? 1e-12f : rs;
  float hr = rs*p2d[(long)n*256+j] + scat2[(long)n*256+j];
  float xo = hr/denom; xo = xo > 0.f ? xo : (expf(xo) - 1.f);
  float xl = hr > 0.f ? hr : (expf(hr) - 1.f);
  float val = eu[(long)n*256+j] + mask[n]*xo;
  float n1 = block_sum<256>(val*val);
  float n2 = block_sum<256>(xl*xl);
  stf(out, (long)n*256 + j, val/fmaxf(sqrtf(n1), 1e-12f), f32);
  stf(out, 12865536L + (long)n*256 + j, xl/fmaxf(sqrtf(n2), 1e-12f), f32);
}

extern "C" void kernel_launch(void* const* d_in, const int* in_sizes, int n_in,
                              void* d_out, int out_size, void* d_ws, size_t ws_size,
                              hipStream_t stream) {
  const void* emb = d_in[0];
  const void* rel = d_in[1];
  const void* a1b = d_in[2];
  const void* a21 = d_in[3];
  const void* W   = d_in[4];
  const void* aout= d_in[5];
  const void* a2o = d_in[6];
  const void* We  = d_in[7];
  const int* bi   = (const int*)d_in[8];
  const int* el   = (const int*)d_in[9];
  const int* et   = (const int*)d_in[10];
  const int* eln  = (const int*)d_in[11];
  const int* etn  = (const int*)d_in[12];
  float* ws = (float*)d_ws;

  // R4's proven layout. TW region [19.2M, ...) is free during layer-1
  // (layer-1 scat is only [12.8M,19.2M)); it is reused for layer-1 weight
  // transposes, then overwritten by the layer-2 transposes, then clobbered
  // by the layer-2 scat memset AFTER projT has consumed it.
  const size_t PD_=0, PS_=6400000;            // layer-1 per-head pd|ps [0,12.8M)
  const size_t P2D_=0;                         // layer-2 p2d overlays [0,12.8M)
  const size_t SC_=12800000;                   // scat (layer1: 6.4M, layer2: 12.8M)
  const size_t TW_=19200000;                   // transposed weights
  const size_t X_=25600000;                    // x fp32 [25.6M,38.4M)
  const size_t P2S_=38400000;                  // layer-2 ps, later eu
  const size_t XN_=38400000;                   // xnorm fp32 (layer-1 only; P2S_ region is
                                               // free until layer-2 projT writes O2 there)
  const size_t RS1_=51200000, SD_=51250000, SS_=51300000, S2D_=51350000,
               S2S_=51400000, RS2_=51450000, MK_=51500000,
               RP1_=51550000, SR1_=51590000, R2_=51600000, RP2_=51670000,
               SR2_=51740000, FLAG_=51750000;
  int* flag = (int*)(ws + FLAG_);

  k_detect<<<1,1,0,stream>>>(emb, flag);

  hipMemsetAsync(ws+RS2_, 0, (size_t)50000*sizeof(float), stream);
  hipMemsetAsync(ws+MK_,  0, (size_t)50000*sizeof(float), stream);

  // xnorm once (shared by both heads), + transpose all 4 layer-1 weight blocks
  k_norm<<<N_NODES,128,0,stream>>>(emb, flag, ws+XN_);
  k_trF<<<128,128,0,stream>>>(a1b, flag, 0L,          384L, 128, ws+TW_);          // h0 a_d
  k_trF<<<128,128,0,stream>>>(a1b, flag, 128L,        384L, 128, ws+TW_+16384);    // h0 a_s
  k_trF<<<128,128,0,stream>>>(a1b, flag, 49152L,      384L, 128, ws+TW_+32768);    // h1 a_d
  k_trF<<<128,128,0,stream>>>(a1b, flag, 49152L+128L, 384L, 128, ws+TW_+49152);    // h1 a_s

  // head 0
  hipMemsetAsync(ws+SC_,  0, (size_t)6400000*sizeof(float), stream);
  hipMemsetAsync(ws+RS1_, 0, (size_t)50000*sizeof(float), stream);
  k_projT<128,128,8><<<(N_NODES+7)/8,128,0,stream>>>(ws+XN_, N_NODES,
                                                     ws+TW_, ws+TW_+16384,
                                                     ws+PD_, ws+PS_, 128);
  k_scoreF<128><<<N_NODES,128,0,stream>>>(ws+PD_, ws+PS_, a21, 0L, flag,
                                          ws+SD_, ws+SS_);
  k_rproj1<<<256,128,0,stream>>>(rel, a1b, a21, flag, ws+RP1_, ws+SR1_);
  k_edge<128><<<(ETOT*64)/256,256,0,stream>>>(el, et, eln, etn, ws+PS_, ws+RP1_,
                                              ws+SD_, ws+SS_, ws+SR1_, ws+SC_, ws+RS1_);
  k_fin1<<<N_NODES,128,0,stream>>>(ws+PD_, ws+SC_, ws+RS1_, ws+X_, 0);

  // head 1
  hipMemsetAsync(ws+SC_,  0, (size_t)6400000*sizeof(float), stream);
  hipMemsetAsync(ws+RS1_, 0, (size_t)50000*sizeof(float), stream);
  k_projT<128,128,8><<<(N_NODES+7)/8,128,0,stream>>>(ws+XN_, N_NODES,
                                                     ws+TW_+32768, ws+TW_+49152,
                                                     ws+PD_, ws+PS_, 128);
  k_scoreF<128><<<N_NODES,128,0,stream>>>(ws+PD_, ws+PS_, a21, 128L, flag,
                                          ws+SD_, ws+SS_);
  k_rproj1b<<<256,128,0,stream>>>(rel, a1b, a21, flag, 49152L, 128L, ws+RP1_, ws+SR1_);
  k_edge<128><<<(ETOT*64)/256,256,0,stream>>>(el, et, eln, etn, ws+PS_, ws+RP1_,
                                              ws+SD_, ws+SS_, ws+SR1_, ws+SC_, ws+RS1_);
  k_fin1<<<N_NODES,128,0,stream>>>(ws+PD_, ws+SC_, ws+RS1_, ws+X_, 128);

  k_rel2<<<256,256,0,stream>>>(rel, W, flag, ws+R2_, d_out);
  k_rproj2<<<256,256,0,stream>>>(ws+R2_, aout, a2o, flag, ws+RP2_, ws+SR2_);

  // layer-2 projection (transpose + coalesced projT + score)
  k_trF<<<256,256,0,stream>>>(aout, flag, 0L,   768L, 256, ws+TW_);
  k_trF<<<256,256,0,stream>>>(aout, flag, 256L, 768L, 256, ws+TW_+65536);
  k_projT<256,256,8><<<(N_NODES+7)/8,256,0,stream>>>(ws+X_, N_NODES,
                                                     ws+TW_, ws+TW_+65536,
                                                     ws+P2D_, ws+P2S_, 256);
  k_scoreF<256><<<N_NODES,256,0,stream>>>(ws+P2D_, ws+P2S_, a2o, 0L, flag,
                                          ws+S2D_, ws+S2S_);

  hipMemsetAsync(ws+SC_, 0, (size_t)12800000*sizeof(float), stream);
  k_edge<256><<<(ETOT*64)/256,256,0,stream>>>(el, et, eln, etn, ws+P2S_, ws+RP2_,
                                              ws+S2D_, ws+S2S_, ws+SR2_, ws+SC_, ws+RS2_);
  k_mask<<<16,256,0,stream>>>(bi, ws+MK_);
  k_entup<<<N_NODES,256,0,stream>>>(emb, We, flag, ws+P2S_);
  k_final<<<N_NODES,256,0,stream>>>(ws+P2D_, ws+SC_, ws+RS2_, ws+P2S_, ws+MK_, flag, d_out);
}

// Round 2
// 1397.957 us; speedup vs baseline: 8.0832x; 1.2235x over previous
//
#include <hip/hip_runtime.h>
#include <hip/hip_bf16.h>
#include <math.h>

#define N_NODES 50000
#define E1 300000
#define EN 30000
#define ETOT 330000

typedef __hip_bfloat16 bf16;

__device__ __forceinline__ float b2f(bf16 x){ return __bfloat162float(x); }
__device__ __forceinline__ bf16 f2b(float x){ return __float2bfloat16(x); }

// dual-dtype load/store: f32==true -> buffer is float32, else bf16
__device__ __forceinline__ float ldf(const void* p, long i, bool f32){
  return f32 ? ((const float*)p)[i] : b2f(((const bf16*)p)[i]);
}
__device__ __forceinline__ void stf(void* p, long i, float v, bool f32){
  if (f32) ((float*)p)[i] = v; else ((bf16*)p)[i] = f2b(v);
}

template<int NT>
__device__ __forceinline__ float block_sum(float v){
  __shared__ float sm[NT/64];
  #pragma unroll
  for (int o=32;o>0;o>>=1) v += __shfl_down(v,o);
  if ((threadIdx.x & 63)==0) sm[threadIdx.x>>6] = v;
  __syncthreads();
  float t = 0.f;
  #pragma unroll
  for (int w=0;w<NT/64;w++) t += sm[w];
  __syncthreads();
  return t;
}

// Detect input dtype (proven in R4): flag=0 -> bf16, flag=1 -> fp32
__global__ void k_detect(const void* __restrict__ emb, int* __restrict__ flag){
  const unsigned short* h = (const unsigned short*)emb;
  int sane = 0;
  for (int i=0;i<128;i++){
    unsigned e = (h[i]>>7)&0xFFu;
    if (e>=112u && e<=143u) sane++;
  }
  *flag = (sane >= 112) ? 0 : 1;
}

// Layer-1 relation projection: rp[t] fp32, sr[t]
__global__ void k_rproj1(const void* __restrict__ rel, const void* __restrict__ a,
                         const void* __restrict__ a2, const int* __restrict__ flag,
                         float* __restrict__ rp, float* __restrict__ sr){
  bool f32 = flag[0] != 0;
  int t = blockIdx.x, j = threadIdx.x;   // 128 threads
  __shared__ float rs_[128];
  rs_[j] = ldf(rel, (long)t*128 + j, f32);
  __syncthreads();
  long ar = (long)j*384 + 256;
  float acc = 0.f;
  #pragma unroll 4
  for (int k=0;k<128;k++) acc += rs_[k]*ldf(a, ar+k, f32);
  rp[(long)t*128+j] = acc;
  float v = block_sum<128>(acc*ldf(a2, j, f32));
  if (j==0) sr[t] = v;
}

__global__ void k_rproj1b(const void* __restrict__ rel, const void* __restrict__ a,
                          const void* __restrict__ a2, const int* __restrict__ flag,
                          long abias, long a2bias,
                          float* __restrict__ rp, float* __restrict__ sr){
  bool f32 = flag[0] != 0;
  int t = blockIdx.x, j = threadIdx.x;
  __shared__ float rs_[128];
  rs_[j] = ldf(rel, (long)t*128 + j, f32);
  __syncthreads();
  long ar = abias + (long)j*384 + 256;
  float acc = 0.f;
  #pragma unroll 4
  for (int k=0;k<128;k++) acc += rs_[k]*ldf(a, ar+k, f32);
  rp[(long)t*128+j] = acc;
  float v = block_sum<128>(acc*ldf(a2, a2bias + j, f32));
  if (j==0) sr[t] = v;
}

// Edge scatter: one wave/edge. w=exp(-lrelu(score)); scat[dst] += w*(ps[src]+rp[type])
template<int D>
__global__ void k_edge(const int* __restrict__ el, const int* __restrict__ et,
                       const int* __restrict__ eln, const int* __restrict__ etn,
                       const float* __restrict__ ps, const float* __restrict__ rp,
                       const float* __restrict__ sd, const float* __restrict__ ss,
                       const float* __restrict__ sr,
                       float* __restrict__ scat, float* __restrict__ rowsum){
  long gid = (long)blockIdx.x*blockDim.x + threadIdx.x;
  long wid = gid >> 6;
  int lane = threadIdx.x & 63;
  if (wid >= ETOT) return;
  int dst, src; const float *pr1, *pr2 = nullptr; float srv;
  if (wid < E1){
    int e = (int)wid;
    dst = el[e]; src = el[E1 + e];
    int t = et[e]; pr1 = rp + (long)t*D; srv = sr[t];
  } else {
    int e = (int)wid - E1;
    dst = eln[e]; src = eln[EN + e];
    int t0 = etn[2*e], t1 = etn[2*e+1];
    pr1 = rp + (long)t0*D; pr2 = rp + (long)t1*D; srv = sr[t0] + sr[t1];
  }
  float score = sd[dst] + ss[src] + srv;
  float lr = score > 0.f ? score : 0.2f*score;
  float w = expf(-lr);
  if (lane == 0) atomicAdd(rowsum + dst, w);
  const float* psr = ps + (long)src*D;
  float* outp = scat + (long)dst*D;
  if (pr2){
    #pragma unroll
    for (int j=lane; j<D; j+=64) atomicAdd(outp+j, w*(psr[j] + pr1[j] + pr2[j]));
  } else {
    #pragma unroll
    for (int j=lane; j<D; j+=64) atomicAdd(outp+j, w*(psr[j] + pr1[j]));
  }
}

// Layer-1 finalize: x[:, hoff+j] = elu((rs*pd + scat)/denom), fp32
__global__ void k_fin1(const float* __restrict__ pd, const float* __restrict__ scat,
                       const float* __restrict__ rowsum, float* __restrict__ x, int hoff){
  int n = blockIdx.x, j = threadIdx.x;   // 128 threads
  float rs = rowsum[n];
  float denom = (rs == 0.f) ? 1e-12f : rs;
  float hr = rs*pd[(long)n*128+j] + scat[(long)n*128+j];
  float hv = hr/denom;
  hv = hv > 0.f ? hv : (expf(hv) - 1.f);
  x[(long)n*256 + hoff + j] = hv;
}

// out_relation_1 = rel @ W  (fp32 copy to ws + dual-dtype output at element offset)
__global__ void k_rel2(const void* __restrict__ rel, const void* __restrict__ W,
                       const int* __restrict__ flag,
                       float* __restrict__ r2, void* __restrict__ out){
  bool f32 = flag[0] != 0;
  int t = blockIdx.x, j = threadIdx.x;   // 256 threads
  __shared__ float rs_[128];
  if (j < 128) rs_[j] = ldf(rel, (long)t*128 + j, f32);
  __syncthreads();
  float acc = 0.f;
  #pragma unroll 4
  for (int k=0;k<128;k++) acc += rs_[k]*ldf(W, (long)k*256 + j, f32);
  r2[(long)t*256+j] = acc;
  stf(out, 12800000L + (long)t*256 + j, acc, f32);
}

// Layer-2 relation projection: rp2 fp32, sr2
__global__ void k_rproj2(const float* __restrict__ r2, const void* __restrict__ a,
                         const void* __restrict__ a2, const int* __restrict__ flag,
                         float* __restrict__ rp, float* __restrict__ sr){
  bool f32 = flag[0] != 0;
  int t = blockIdx.x, j = threadIdx.x;   // 256 threads
  __shared__ float rs_[256];
  rs_[j] = r2[(long)t*256 + j];
  __syncthreads();
  long ar = (long)j*768 + 512;
  float acc = 0.f;
  #pragma unroll 4
  for (int k=0;k<256;k++) acc += rs_[k]*ldf(a, ar+k, f32);
  rp[(long)t*256+j] = acc;
  float v = block_sum<256>(acc*ldf(a2, j, f32));
  if (j==0) sr[t] = v;
}

// Transpose weight block to fp32 [k][J]: dst[k*J+j] = src[bias + j*jstride + k]
__global__ void k_trF(const void* __restrict__ src, const int* __restrict__ flag,
                      long bias, long jstride, int J, float* __restrict__ dst){
  bool f32 = flag[0] != 0;
  int k = blockIdx.x, j = threadIdx.x;
  dst[(long)k*J + j] = ldf(src, bias + (long)j*jstride + k, f32);
}

// Convert-only (no transpose) to fp32: dst[i] = src[i]
__global__ void k_cvtF(const void* __restrict__ src, const int* __restrict__ flag,
                       int n, float* __restrict__ dst){
  bool f32 = flag[0] != 0;
  int i = blockIdx.x*blockDim.x + threadIdx.x;
  if (i < n) dst[i] = ldf(src, i, f32);
}

// Unified GEMM kernel: stage BM rows of X in LDS (optional fused l2norm),
// O1 = Xn @ WT1 (coalesced [k][NT] weights), optionally O2 = Xn @ WT2,
// optionally fused score s1[n]=dot(O1[n,:],a2), s2[n]=dot(O2[n,:],a2).
// XDUAL: X dtype follows flag; else X is fp32.
template<int NT, int K, int BM, int NORM, int DUAL, int SCORE, int XDUAL>
__global__ __launch_bounds__(NT) void k_gnp(
    const void* __restrict__ X, const int* __restrict__ flag, int N,
    const float* __restrict__ WT1, const float* __restrict__ WT2,
    const void* __restrict__ a2, long a2bias,
    float* __restrict__ O1, float* __restrict__ O2,
    float* __restrict__ s1, float* __restrict__ s2, int ldc){
  __shared__ float xs[BM][K];
  __shared__ float rsc[BM];
  const int NW = NT/64;
  __shared__ float red1[BM][NW];
  __shared__ float red2[BM][NW];
  int t = threadIdx.x;
  int n0 = blockIdx.x * BM;
  bool xf32 = XDUAL ? (flag[0] != 0) : true;

  for (int idx = t; idx < BM*K; idx += NT){
    int m = idx / K, k = idx - m*K;
    int n = n0 + m;
    xs[m][k] = (n < N) ? ldf(X, (long)n*K + k, xf32) : 0.f;
  }
  __syncthreads();

  if (NORM){
    const int NPR = NT / BM;            // threads per row (8 or 16; <=32)
    int r = t / NPR, l = t - r*NPR;
    float ssq = 0.f;
    #pragma unroll
    for (int k = l; k < K; k += NPR){ float v = xs[r][k]; ssq += v*v; }
    #pragma unroll
    for (int o = NPR>>1; o > 0; o >>= 1) ssq += __shfl_xor(ssq, o);
    if (l == 0) rsc[r] = 1.f / fmaxf(sqrtf(ssq), 1e-12f);
    __syncthreads();
    for (int idx = t; idx < BM*K; idx += NT){
      int m = idx / K, k = idx - m*K;
      xs[m][k] *= rsc[m];
    }
    __syncthreads();
  }

  float a1c[BM], a2c[BM];
  #pragma unroll
  for (int m=0;m<BM;m++){ a1c[m]=0.f; a2c[m]=0.f; }
  #pragma unroll 4
  for (int k=0;k<K;k++){
    float w1 = WT1[(long)k*NT + t];
    float w2 = DUAL ? WT2[(long)k*NT + t] : 0.f;
    #pragma unroll
    for (int m=0;m<BM;m++){
      a1c[m] += xs[m][k]*w1;
      if (DUAL) a2c[m] += xs[m][k]*w2;
    }
  }

  #pragma unroll
  for (int m=0;m<BM;m++){
    int n = n0 + m;
    if (n < N){
      O1[(long)n*ldc + t] = a1c[m];
      if (DUAL) O2[(long)n*ldc + t] = a2c[m];
    }
  }

  if (SCORE){
    bool af32 = flag[0] != 0;
    float a2v = ldf(a2, a2bias + t, af32);
    int w = t >> 6, lane = t & 63;
    #pragma unroll
    for (int m=0;m<BM;m++){
      float v1 = a1c[m]*a2v;
      float v2 = DUAL ? a2c[m]*a2v : 0.f;
      #pragma unroll
      for (int o=32;o>0;o>>=1){ v1 += __shfl_down(v1,o); v2 += __shfl_down(v2,o); }
      if (lane==0){ red1[m][w]=v1; red2[m][w]=v2; }
    }
    __syncthreads();
    if (t < BM && n0 + t < N){
      float v1=0.f, v2=0.f;
      #pragma unroll
      for (int ww=0;ww<NW;ww++){ v1+=red1[t][ww]; v2+=red2[t][ww]; }
      s1[n0+t] = v1;
      if (DUAL) s2[n0+t] = v2;
    }
  }
}

__global__ void k_mask(const int* __restrict__ bi, float* __restrict__ mask){
  int i = blockIdx.x*blockDim.x + threadIdx.x;
  if (i < 4096) mask[bi[i*3 + 2]] = 1.f;
}

// Final: out0 = l2norm(eu + mask*elu(hraw/denom)), out2 = l2norm(elu(hraw))
__global__ void k_final(const float* __restrict__ p2d, const float* __restrict__ scat2,
                        const float* __restrict__ rowsum2, const float* __restrict__ eu,
                        const float* __restrict__ mask, const int* __restrict__ flag,
                        void* __restrict__ out){
  bool f32 = flag[0] != 0;
  int n = blockIdx.x, j = threadIdx.x;   // 256 threads
  float rs = rowsum2[n];
  float denom = (rs == 0.f) ? 1e-12f : rs;
  float hr = rs*p2d[(long)n*256+j] + scat2[(long)n*256+j];
  float xo = hr/denom; xo = xo > 0.f ? xo : (expf(xo) - 1.f);
  float xl = hr > 0.f ? hr : (expf(hr) - 1.f);
  float val = eu[(long)n*256+j] + mask[n]*xo;
  float n1 = block_sum<256>(val*val);
  float n2 = block_sum<256>(xl*xl);
  stf(out, (long)n*256 + j, val/fmaxf(sqrtf(n1), 1e-12f), f32);
  stf(out, 12865536L + (long)n*256 + j, xl/fmaxf(sqrtf(n2), 1e-12f), f32);
}

extern "C" void kernel_launch(void* const* d_in, const int* in_sizes, int n_in,
                              void* d_out, int out_size, void* d_ws, size_t ws_size,
                              hipStream_t stream) {
  const void* emb = d_in[0];
  const void* rel = d_in[1];
  const void* a1b = d_in[2];
  const void* a21 = d_in[3];
  const void* W   = d_in[4];
  const void* aout= d_in[5];
  const void* a2o = d_in[6];
  const void* We  = d_in[7];
  const int* bi   = (const int*)d_in[8];
  const int* el   = (const int*)d_in[9];
  const int* et   = (const int*)d_in[10];
  const int* eln  = (const int*)d_in[11];
  const int* etn  = (const int*)d_in[12];
  float* ws = (float*)d_ws;

  // Workspace layout (liveness-checked):
  //  [0,12.8M)      layer-1 pd|ps per head  -> layer-2 p2d (live to k_final)
  //  [12.8M,25.6M)  scat (layer1 uses first half; layer2 all of it)
  //  TW_=19.2M      transposed weights (dead zone of layer-1 scat region;
  //                 clobbered by layer-2 scat memset AFTER projT consumed it)
  //  X_=25.6M       x fp32 (dead after layer-2 k_gnp; then reused for WeT fp32)
  //  P2S_=38.4M     layer-2 ps (consumed by edge2), then eu (live to k_final)
  const size_t PD_=0, PS_=6400000;
  const size_t P2D_=0;
  const size_t SC_=12800000;
  const size_t TW_=19200000;
  const size_t X_=25600000;
  const size_t P2S_=38400000;
  const size_t RS1_=51200000, SD_=51250000, SS_=51300000, S2D_=51350000,
               S2S_=51400000, RS2_=51450000, MK_=51500000,
               RP1_=51550000, SR1_=51590000, R2_=51600000, RP2_=51670000,
               SR2_=51740000, FLAG_=51750000;
  int* flag = (int*)(ws + FLAG_);

  k_detect<<<1,1,0,stream>>>(emb, flag);

  hipMemsetAsync(ws+RS2_, 0, (size_t)50000*sizeof(float), stream);
  hipMemsetAsync(ws+MK_,  0, (size_t)50000*sizeof(float), stream);

  // transpose the 4 layer-1 node-weight blocks to fp32 [k][128]
  k_trF<<<128,128,0,stream>>>(a1b, flag, 0L,          384L, 128, ws+TW_);          // h0 a_d
  k_trF<<<128,128,0,stream>>>(a1b, flag, 128L,        384L, 128, ws+TW_+16384);    // h0 a_s
  k_trF<<<128,128,0,stream>>>(a1b, flag, 49152L,      384L, 128, ws+TW_+32768);    // h1 a_d
  k_trF<<<128,128,0,stream>>>(a1b, flag, 49152L+128L, 384L, 128, ws+TW_+49152);    // h1 a_s

  // head 0: fused norm + dual projection + score
  hipMemsetAsync(ws+SC_,  0, (size_t)6400000*sizeof(float), stream);
  hipMemsetAsync(ws+RS1_, 0, (size_t)50000*sizeof(float), stream);
  k_gnp<128,128,16,1,1,1,1><<<(N_NODES+15)/16,128,0,stream>>>(
      emb, flag, N_NODES, ws+TW_, ws+TW_+16384, a21, 0L,
      ws+PD_, ws+PS_, ws+SD_, ws+SS_, 128);
  k_rproj1<<<256,128,0,stream>>>(rel, a1b, a21, flag, ws+RP1_, ws+SR1_);
  k_edge<128><<<(ETOT*64)/256,256,0,stream>>>(el, et, eln, etn, ws+PS_, ws+RP1_,
                                              ws+SD_, ws+SS_, ws+SR1_, ws+SC_, ws+RS1_);
  k_fin1<<<N_NODES,128,0,stream>>>(ws+PD_, ws+SC_, ws+RS1_, ws+X_, 0);

  // head 1
  hipMemsetAsync(ws+SC_,  0, (size_t)6400000*sizeof(float), stream);
  hipMemsetAsync(ws+RS1_, 0, (size_t)50000*sizeof(float), stream);
  k_gnp<128,128,16,1,1,1,1><<<(N_NODES+15)/16,128,0,stream>>>(
      emb, flag, N_NODES, ws+TW_+32768, ws+TW_+49152, a21, 128L,
      ws+PD_, ws+PS_, ws+SD_, ws+SS_, 128);
  k_rproj1b<<<256,128,0,stream>>>(rel, a1b, a21, flag, 49152L, 128L, ws+RP1_, ws+SR1_);
  k_edge<128><<<(ETOT*64)/256,256,0,stream>>>(el, et, eln, etn, ws+PS_, ws+RP1_,
                                              ws+SD_, ws+SS_, ws+SR1_, ws+SC_, ws+RS1_);
  k_fin1<<<N_NODES,128,0,stream>>>(ws+PD_, ws+SC_, ws+RS1_, ws+X_, 128);

  k_rel2<<<256,256,0,stream>>>(rel, W, flag, ws+R2_, d_out);
  k_rproj2<<<256,256,0,stream>>>(ws+R2_, aout, a2o, flag, ws+RP2_, ws+SR2_);

  // layer-2 projection: transpose + fused dual projT + score
  k_trF<<<256,256,0,stream>>>(aout, flag, 0L,   768L, 256, ws+TW_);
  k_trF<<<256,256,0,stream>>>(aout, flag, 256L, 768L, 256, ws+TW_+65536);
  k_gnp<256,256,16,0,1,1,0><<<(N_NODES+15)/16,256,0,stream>>>(
      ws+X_, flag, N_NODES, ws+TW_, ws+TW_+65536, a2o, 0L,
      ws+P2D_, ws+P2S_, ws+S2D_, ws+S2S_, 256);

  // x is dead now -> reuse X_ for fp32 We (already [k][256] layout, convert only)
  k_cvtF<<<128,256,0,stream>>>(We, flag, 32768, ws+X_);

  hipMemsetAsync(ws+SC_, 0, (size_t)12800000*sizeof(float), stream);
  k_edge<256><<<(ETOT*64)/256,256,0,stream>>>(el, et, eln, etn, ws+P2S_, ws+RP2_,
                                              ws+S2D_, ws+S2S_, ws+SR2_, ws+SC_, ws+RS2_);
  k_mask<<<16,256,0,stream>>>(bi, ws+MK_);

  // entities_upgraded: fused norm + single projection (We pre-converted), eu -> P2S_
  k_gnp<256,128,16,1,0,0,1><<<(N_NODES+15)/16,256,0,stream>>>(
      emb, flag, N_NODES, ws+X_, nullptr, nullptr, 0L,
      ws+P2S_, nullptr, nullptr, nullptr, 256);

  k_final<<<N_NODES,256,0,stream>>>(ws+P2D_, ws+SC_, ws+RS2_, ws+P2S_, ws+MK_, flag, d_out);
}

// Round 3
// 1109.332 us; speedup vs baseline: 10.1863x; 1.2602x over previous
//
#include <hip/hip_runtime.h>
#include <hip/hip_bf16.h>
#include <math.h>

#define N_NODES 50000
#define E1 300000
#define EN 30000
#define ETOT 330000

typedef __hip_bfloat16 bf16;

__device__ __forceinline__ float b2f(bf16 x){ return __bfloat162float(x); }
__device__ __forceinline__ bf16 f2b(float x){ return __float2bfloat16(x); }

__device__ __forceinline__ float ldf(const void* p, long i, bool f32){
  return f32 ? ((const float*)p)[i] : b2f(((const bf16*)p)[i]);
}
__device__ __forceinline__ void stf(void* p, long i, float v, bool f32){
  if (f32) ((float*)p)[i] = v; else ((bf16*)p)[i] = f2b(v);
}

template<int NT>
__device__ __forceinline__ float block_sum(float v){
  __shared__ float sm[NT/64];
  #pragma unroll
  for (int o=32;o>0;o>>=1) v += __shfl_down(v,o);
  if ((threadIdx.x & 63)==0) sm[threadIdx.x>>6] = v;
  __syncthreads();
  float t = 0.f;
  #pragma unroll
  for (int w=0;w<NT/64;w++) t += sm[w];
  __syncthreads();
  return t;
}

// Detect input dtype: flag=0 -> bf16, flag=1 -> fp32
__global__ void k_detect(const void* __restrict__ emb, int* __restrict__ flag){
  const unsigned short* h = (const unsigned short*)emb;
  int sane = 0;
  for (int i=0;i<128;i++){
    unsigned e = (h[i]>>7)&0xFFu;
    if (e>=112u && e<=143u) sane++;
  }
  *flag = (sane >= 112) ? 0 : 1;
}

// ---- CSR build (by dst), shared by all 3 edge passes ----
__global__ void k_hist(const int* __restrict__ el, const int* __restrict__ eln,
                       int* __restrict__ cnt){
  int i = blockIdx.x*blockDim.x + threadIdx.x;
  if (i < ETOT){
    int dst = (i < E1) ? el[i] : eln[i - E1];
    atomicAdd(cnt + dst, 1);
  }
}

// single block, 1024 threads: exclusive scan of cnt -> rowp, cursor copy
__global__ __launch_bounds__(1024) void k_scan(const int* __restrict__ cnt,
                                               int* __restrict__ rowp,
                                               int* __restrict__ cur){
  __shared__ int part[1024];
  int t = threadIdx.x;
  const int CH = (N_NODES + 1023)/1024;   // 49
  int base = t*CH;
  int s = 0;
  for (int i=0;i<CH;i++){ int n = base+i; if (n < N_NODES) s += cnt[n]; }
  part[t] = s;
  __syncthreads();
  for (int o=1;o<1024;o<<=1){
    int u = (t>=o) ? part[t-o] : 0;
    __syncthreads();
    part[t] += u;
    __syncthreads();
  }
  int off = part[t] - s;                  // exclusive prefix of this chunk
  for (int i=0;i<CH;i++){
    int n = base+i;
    if (n < N_NODES){ rowp[n] = off; cur[n] = off; off += cnt[n]; }
  }
  if (t==0) rowp[N_NODES] = ETOT;
}

__global__ void k_fill(const int* __restrict__ el, const int* __restrict__ et,
                       const int* __restrict__ eln, const int* __restrict__ etn,
                       int* __restrict__ cur, int* __restrict__ esrc,
                       int* __restrict__ epak){
  int i = blockIdx.x*blockDim.x + threadIdx.x;
  if (i >= ETOT) return;
  int dst, src, pk;
  if (i < E1){
    dst = el[i]; src = el[E1 + i];
    pk = et[i];
  } else {
    int e = i - E1;
    dst = eln[e]; src = eln[EN + e];
    pk = etn[2*e] | (etn[2*e+1]<<9) | (1<<18);
  }
  int pos = atomicAdd(cur + dst, 1);
  esrc[pos] = src; epak[pos] = pk;
}

// ---- gather (replaces k_edge + k_fin1): one wave per dst node ----
// x[n,hoff+j] = elu((rs*pd[n,j] + sum_e w*(ps[src,j]+rp[t,j]))/denom)
template<int D>
__global__ __launch_bounds__(256) void k_gath1(
    const int* __restrict__ rowp, const int* __restrict__ esrc,
    const int* __restrict__ epak,
    const float* __restrict__ pd, const float* __restrict__ ps,
    const float* __restrict__ rp,
    const float* __restrict__ sd, const float* __restrict__ ss,
    const float* __restrict__ sr,
    float* __restrict__ x, int hoff){
  int w = threadIdx.x >> 6, lane = threadIdx.x & 63;
  int n = blockIdx.x*4 + w;
  if (n >= N_NODES) return;
  const int M = D/64;
  float acc[M];
  #pragma unroll
  for (int m=0;m<M;m++) acc[m] = 0.f;
  float rs = 0.f;
  float sdn = sd[n];
  int b = rowp[n], e = rowp[n+1];
  for (int i=b;i<e;i++){
    int src = esrc[i], pk = epak[i];
    int t0 = pk & 511, t1 = (pk>>9)&511, has2 = (pk>>18)&1;
    float srv = sr[t0] + (has2 ? sr[t1] : 0.f);
    float score = sdn + ss[src] + srv;
    float lr = score > 0.f ? score : 0.2f*score;
    float wgt = expf(-lr);
    rs += wgt;
    const float* psr = ps + (long)src*D;
    const float* r1  = rp + (long)t0*D;
    const float* r2  = rp + (long)t1*D;
    #pragma unroll
    for (int m=0;m<M;m++){
      float v = psr[m*64+lane] + r1[m*64+lane];
      if (has2) v += r2[m*64+lane];
      acc[m] += wgt*v;
    }
  }
  float denom = (rs == 0.f) ? 1e-12f : rs;
  #pragma unroll
  for (int m=0;m<M;m++){
    int j = m*64+lane;
    float hr = rs*pd[(long)n*D + j] + acc[m];
    float hv = hr/denom;
    hv = hv > 0.f ? hv : (expf(hv) - 1.f);
    x[(long)n*256 + hoff + j] = hv;
  }
}

// ---- gather layer-2 (replaces k_edge + k_final): fused epilogue ----
__global__ __launch_bounds__(256) void k_gath2(
    const int* __restrict__ rowp, const int* __restrict__ esrc,
    const int* __restrict__ epak,
    const float* __restrict__ p2d, const float* __restrict__ ps,
    const float* __restrict__ rp,
    const float* __restrict__ sd, const float* __restrict__ ss,
    const float* __restrict__ sr,
    const float* __restrict__ eu, const float* __restrict__ mask,
    const int* __restrict__ flag, void* __restrict__ out){
  bool f32 = flag[0] != 0;
  int w = threadIdx.x >> 6, lane = threadIdx.x & 63;
  int n = blockIdx.x*4 + w;
  if (n >= N_NODES) return;
  float acc[4] = {0.f,0.f,0.f,0.f};
  float rs = 0.f;
  float sdn = sd[n];
  int b = rowp[n], e = rowp[n+1];
  for (int i=b;i<e;i++){
    int src = esrc[i], pk = epak[i];
    int t0 = pk & 511, t1 = (pk>>9)&511, has2 = (pk>>18)&1;
    float srv = sr[t0] + (has2 ? sr[t1] : 0.f);
    float score = sdn + ss[src] + srv;
    float lr = score > 0.f ? score : 0.2f*score;
    float wgt = expf(-lr);
    rs += wgt;
    const float* psr = ps + (long)src*256;
    const float* r1  = rp + (long)t0*256;
    const float* r2  = rp + (long)t1*256;
    #pragma unroll
    for (int m=0;m<4;m++){
      float v = psr[m*64+lane] + r1[m*64+lane];
      if (has2) v += r2[m*64+lane];
      acc[m] += wgt*v;
    }
  }
  float denom = (rs == 0.f) ? 1e-12f : rs;
  float mk = mask[n];
  float val[4], xl[4];
  float n1 = 0.f, n2 = 0.f;
  #pragma unroll
  for (int m=0;m<4;m++){
    int j = m*64+lane;
    float hr = rs*p2d[(long)n*256 + j] + acc[m];
    float xo = hr/denom; xo = xo > 0.f ? xo : (expf(xo) - 1.f);
    float l  = hr > 0.f ? hr : (expf(hr) - 1.f);
    float v  = eu[(long)n*256 + j] + mk*xo;
    val[m] = v; xl[m] = l;
    n1 += v*v; n2 += l*l;
  }
  #pragma unroll
  for (int o=32;o>0;o>>=1){ n1 += __shfl_xor(n1,o); n2 += __shfl_xor(n2,o); }
  float i1 = 1.f/fmaxf(sqrtf(n1), 1e-12f);
  float i2 = 1.f/fmaxf(sqrtf(n2), 1e-12f);
  #pragma unroll
  for (int m=0;m<4;m++){
    int j = m*64+lane;
    stf(out, (long)n*256 + j,             val[m]*i1, f32);
    stf(out, 12865536L + (long)n*256 + j, xl[m]*i2,  f32);
  }
}

// Layer-1 relation projection: rp[t] fp32, sr[t]
__global__ void k_rproj1(const void* __restrict__ rel, const void* __restrict__ a,
                         const void* __restrict__ a2, const int* __restrict__ flag,
                         float* __restrict__ rp, float* __restrict__ sr){
  bool f32 = flag[0] != 0;
  int t = blockIdx.x, j = threadIdx.x;   // 128 threads
  __shared__ float rs_[128];
  rs_[j] = ldf(rel, (long)t*128 + j, f32);
  __syncthreads();
  long ar = (long)j*384 + 256;
  float acc = 0.f;
  #pragma unroll 4
  for (int k=0;k<128;k++) acc += rs_[k]*ldf(a, ar+k, f32);
  rp[(long)t*128+j] = acc;
  float v = block_sum<128>(acc*ldf(a2, j, f32));
  if (j==0) sr[t] = v;
}

__global__ void k_rproj1b(const void* __restrict__ rel, const void* __restrict__ a,
                          const void* __restrict__ a2, const int* __restrict__ flag,
                          long abias, long a2bias,
                          float* __restrict__ rp, float* __restrict__ sr){
  bool f32 = flag[0] != 0;
  int t = blockIdx.x, j = threadIdx.x;
  __shared__ float rs_[128];
  rs_[j] = ldf(rel, (long)t*128 + j, f32);
  __syncthreads();
  long ar = abias + (long)j*384 + 256;
  float acc = 0.f;
  #pragma unroll 4
  for (int k=0;k<128;k++) acc += rs_[k]*ldf(a, ar+k, f32);
  rp[(long)t*128+j] = acc;
  float v = block_sum<128>(acc*ldf(a2, a2bias + j, f32));
  if (j==0) sr[t] = v;
}

// out_relation_1 = rel @ W  (fp32 copy to ws + dual-dtype output at element offset)
__global__ void k_rel2(const void* __restrict__ rel, const void* __restrict__ W,
                       const int* __restrict__ flag,
                       float* __restrict__ r2, void* __restrict__ out){
  bool f32 = flag[0] != 0;
  int t = blockIdx.x, j = threadIdx.x;   // 256 threads
  __shared__ float rs_[128];
  if (j < 128) rs_[j] = ldf(rel, (long)t*128 + j, f32);
  __syncthreads();
  float acc = 0.f;
  #pragma unroll 4
  for (int k=0;k<128;k++) acc += rs_[k]*ldf(W, (long)k*256 + j, f32);
  r2[(long)t*256+j] = acc;
  stf(out, 12800000L + (long)t*256 + j, acc, f32);
}

// Layer-2 relation projection: rp2 fp32, sr2
__global__ void k_rproj2(const float* __restrict__ r2, const void* __restrict__ a,
                         const void* __restrict__ a2, const int* __restrict__ flag,
                         float* __restrict__ rp, float* __restrict__ sr){
  bool f32 = flag[0] != 0;
  int t = blockIdx.x, j = threadIdx.x;   // 256 threads
  __shared__ float rs_[256];
  rs_[j] = r2[(long)t*256 + j];
  __syncthreads();
  long ar = (long)j*768 + 512;
  float acc = 0.f;
  #pragma unroll 4
  for (int k=0;k<256;k++) acc += rs_[k]*ldf(a, ar+k, f32);
  rp[(long)t*256+j] = acc;
  float v = block_sum<256>(acc*ldf(a2, j, f32));
  if (j==0) sr[t] = v;
}

// Transpose weight block to fp32 [k][J]: dst[k*J+j] = src[bias + j*jstride + k]
__global__ void k_trF(const void* __restrict__ src, const int* __restrict__ flag,
                      long bias, long jstride, int J, float* __restrict__ dst){
  bool f32 = flag[0] != 0;
  int k = blockIdx.x, j = threadIdx.x;
  dst[(long)k*J + j] = ldf(src, bias + (long)j*jstride + k, f32);
}

// Convert-only (no transpose) to fp32: dst[i] = src[i]
__global__ void k_cvtF(const void* __restrict__ src, const int* __restrict__ flag,
                       int n, float* __restrict__ dst){
  bool f32 = flag[0] != 0;
  int i = blockIdx.x*blockDim.x + threadIdx.x;
  if (i < n) dst[i] = ldf(src, i, f32);
}

// Unified GEMM kernel: stage BM rows of X in LDS (optional fused l2norm),
// O1 = Xn @ WT1, optionally O2 = Xn @ WT2, optionally fused a2-scores.
template<int NT, int K, int BM, int NORM, int DUAL, int SCORE, int XDUAL>
__global__ __launch_bounds__(NT) void k_gnp(
    const void* __restrict__ X, const int* __restrict__ flag, int N,
    const float* __restrict__ WT1, const float* __restrict__ WT2,
    const void* __restrict__ a2, long a2bias,
    float* __restrict__ O1, float* __restrict__ O2,
    float* __restrict__ s1, float* __restrict__ s2, int ldc){
  __shared__ float xs[BM][K];
  __shared__ float rsc[BM];
  const int NW = NT/64;
  __shared__ float red1[BM][NW];
  __shared__ float red2[BM][NW];
  int t = threadIdx.x;
  int n0 = blockIdx.x * BM;
  bool xf32 = XDUAL ? (flag[0] != 0) : true;

  for (int idx = t; idx < BM*K; idx += NT){
    int m = idx / K, k = idx - m*K;
    int n = n0 + m;
    xs[m][k] = (n < N) ? ldf(X, (long)n*K + k, xf32) : 0.f;
  }
  __syncthreads();

  if (NORM){
    const int NPR = NT / BM;
    int r = t / NPR, l = t - r*NPR;
    float ssq = 0.f;
    #pragma unroll
    for (int k = l; k < K; k += NPR){ float v = xs[r][k]; ssq += v*v; }
    #pragma unroll
    for (int o = NPR>>1; o > 0; o >>= 1) ssq += __shfl_xor(ssq, o);
    if (l == 0) rsc[r] = 1.f / fmaxf(sqrtf(ssq), 1e-12f);
    __syncthreads();
    for (int idx = t; idx < BM*K; idx += NT){
      int m = idx / K, k = idx - m*K;
      xs[m][k] *= rsc[m];
    }
    __syncthreads();
  }

  float a1c[BM], a2c[BM];
  #pragma unroll
  for (int m=0;m<BM;m++){ a1c[m]=0.f; a2c[m]=0.f; }
  #pragma unroll 4
  for (int k=0;k<K;k++){
    float w1 = WT1[(long)k*NT + t];
    float w2 = DUAL ? WT2[(long)k*NT + t] : 0.f;
    #pragma unroll
    for (int m=0;m<BM;m++){
      a1c[m] += xs[m][k]*w1;
      if (DUAL) a2c[m] += xs[m][k]*w2;
    }
  }

  #pragma unroll
  for (int m=0;m<BM;m++){
    int n = n0 + m;
    if (n < N){
      O1[(long)n*ldc + t] = a1c[m];
      if (DUAL) O2[(long)n*ldc + t] = a2c[m];
    }
  }

  if (SCORE){
    bool af32 = flag[0] != 0;
    float a2v = ldf(a2, a2bias + t, af32);
    int w = t >> 6, lane = t & 63;
    #pragma unroll
    for (int m=0;m<BM;m++){
      float v1 = a1c[m]*a2v;
      float v2 = DUAL ? a2c[m]*a2v : 0.f;
      #pragma unroll
      for (int o=32;o>0;o>>=1){ v1 += __shfl_down(v1,o); v2 += __shfl_down(v2,o); }
      if (lane==0){ red1[m][w]=v1; red2[m][w]=v2; }
    }
    __syncthreads();
    if (t < BM && n0 + t < N){
      float v1=0.f, v2=0.f;
      #pragma unroll
      for (int ww=0;ww<NW;ww++){ v1+=red1[t][ww]; v2+=red2[t][ww]; }
      s1[n0+t] = v1;
      if (DUAL) s2[n0+t] = v2;
    }
  }
}

__global__ void k_mask(const int* __restrict__ bi, float* __restrict__ mask){
  int i = blockIdx.x*blockDim.x + threadIdx.x;
  if (i < 4096) mask[bi[i*3 + 2]] = 1.f;
}

extern "C" void kernel_launch(void* const* d_in, const int* in_sizes, int n_in,
                              void* d_out, int out_size, void* d_ws, size_t ws_size,
                              hipStream_t stream) {
  const void* emb = d_in[0];
  const void* rel = d_in[1];
  const void* a1b = d_in[2];
  const void* a21 = d_in[3];
  const void* W   = d_in[4];
  const void* aout= d_in[5];
  const void* a2o = d_in[6];
  const void* We  = d_in[7];
  const int* bi   = (const int*)d_in[8];
  const int* el   = (const int*)d_in[9];
  const int* et   = (const int*)d_in[10];
  const int* eln  = (const int*)d_in[11];
  const int* etn  = (const int*)d_in[12];
  float* ws = (float*)d_ws;

  // Workspace layout (liveness-checked):
  //  [0,12.8M)      layer-1 pd|ps per head -> layer-2 p2d (live to k_gath2)
  //  [12.8M,19.2M)  CSR (cnt/cursor, rowp, esrc, epak) — scat region retired
  //  TW_=19.2M      transposed weights (layer-1 then layer-2)
  //  X_=25.6M       x fp32 (dead after layer-2 k_gnp) -> eu (live to k_gath2)
  //  P2S_=38.4M     layer-2 ps2 (live to k_gath2)
  //  RP1_           layer-1 rel proj (dead after gath1) -> We fp32
  const size_t PD_=0, PS_=6400000;
  const size_t P2D_=0;
  const size_t CNT_=12800000, ROWP_=12860000, ESRC_=12920000, EPAK_=13260000;
  const size_t TW_=19200000;
  const size_t X_=25600000;        // x, later eu
  const size_t P2S_=38400000;
  const size_t SD_=51250000, SS_=51300000, S2D_=51350000,
               S2S_=51400000, MK_=51500000,
               RP1_=51550000, SR1_=51590000, R2_=51600000, RP2_=51670000,
               SR2_=51740000, FLAG_=51750000;
  int* flag = (int*)(ws + FLAG_);
  int* cnt  = (int*)(ws + CNT_);
  int* rowp = (int*)(ws + ROWP_);
  int* esrc = (int*)(ws + ESRC_);
  int* epak = (int*)(ws + EPAK_);

  k_detect<<<1,1,0,stream>>>(emb, flag);

  hipMemsetAsync(ws+MK_,  0, (size_t)50000*sizeof(float), stream);
  hipMemsetAsync(cnt,     0, (size_t)50000*sizeof(int), stream);

  // CSR build (once; shared by all 3 edge passes)
  k_hist<<<(ETOT+255)/256,256,0,stream>>>(el, eln, cnt);
  k_scan<<<1,1024,0,stream>>>(cnt, rowp, cnt);   // cnt doubles as cursor after scan
  k_fill<<<(ETOT+255)/256,256,0,stream>>>(el, et, eln, etn, cnt, esrc, epak);

  // transpose the 4 layer-1 node-weight blocks to fp32 [k][128]
  k_trF<<<128,128,0,stream>>>(a1b, flag, 0L,          384L, 128, ws+TW_);
  k_trF<<<128,128,0,stream>>>(a1b, flag, 128L,        384L, 128, ws+TW_+16384);
  k_trF<<<128,128,0,stream>>>(a1b, flag, 49152L,      384L, 128, ws+TW_+32768);
  k_trF<<<128,128,0,stream>>>(a1b, flag, 49152L+128L, 384L, 128, ws+TW_+49152);

  // head 0: fused norm + dual projection + score, then gather (fused fin1)
  k_gnp<128,128,16,1,1,1,1><<<(N_NODES+15)/16,128,0,stream>>>(
      emb, flag, N_NODES, ws+TW_, ws+TW_+16384, a21, 0L,
      ws+PD_, ws+PS_, ws+SD_, ws+SS_, 128);
  k_rproj1<<<256,128,0,stream>>>(rel, a1b, a21, flag, ws+RP1_, ws+SR1_);
  k_gath1<128><<<(N_NODES+3)/4,256,0,stream>>>(rowp, esrc, epak,
      ws+PD_, ws+PS_, ws+RP1_, ws+SD_, ws+SS_, ws+SR1_, ws+X_, 0);

  // head 1
  k_gnp<128,128,16,1,1,1,1><<<(N_NODES+15)/16,128,0,stream>>>(
      emb, flag, N_NODES, ws+TW_+32768, ws+TW_+49152, a21, 128L,
      ws+PD_, ws+PS_, ws+SD_, ws+SS_, 128);
  k_rproj1b<<<256,128,0,stream>>>(rel, a1b, a21, flag, 49152L, 128L, ws+RP1_, ws+SR1_);
  k_gath1<128><<<(N_NODES+3)/4,256,0,stream>>>(rowp, esrc, epak,
      ws+PD_, ws+PS_, ws+RP1_, ws+SD_, ws+SS_, ws+SR1_, ws+X_, 128);

  k_rel2<<<256,256,0,stream>>>(rel, W, flag, ws+R2_, d_out);
  k_rproj2<<<256,256,0,stream>>>(ws+R2_, aout, a2o, flag, ws+RP2_, ws+SR2_);

  // layer-2 projection: transpose + fused dual projT + score
  k_trF<<<256,256,0,stream>>>(aout, flag, 0L,   768L, 256, ws+TW_);
  k_trF<<<256,256,0,stream>>>(aout, flag, 256L, 768L, 256, ws+TW_+65536);
  k_gnp<256,256,16,0,1,1,0><<<(N_NODES+15)/16,256,0,stream>>>(
      ws+X_, flag, N_NODES, ws+TW_, ws+TW_+65536, a2o, 0L,
      ws+P2D_, ws+P2S_, ws+S2D_, ws+S2S_, 256);

  // x dead now. We fp32 -> RP1_ (rp1 dead); eu -> X_ (x dead)
  k_cvtF<<<128,256,0,stream>>>(We, flag, 32768, ws+RP1_);
  k_mask<<<16,256,0,stream>>>(bi, ws+MK_);
  k_gnp<256,128,16,1,0,0,1><<<(N_NODES+15)/16,256,0,stream>>>(
      emb, flag, N_NODES, ws+RP1_, nullptr, nullptr, 0L,
      ws+X_, nullptr, nullptr, nullptr, 256);

  // layer-2 gather with fused final epilogue -> d_out
  k_gath2<<<(N_NODES+3)/4,256,0,stream>>>(rowp, esrc, epak,
      ws+P2D_, ws+P2S_, ws+RP2_, ws+S2D_, ws+S2S_, ws+SR2_,
      ws+X_, ws+MK_, flag, d_out);
}

// Round 4
// 1105.817 us; speedup vs baseline: 10.2187x; 1.0032x over previous
//
#include <hip/hip_runtime.h>
#include <hip/hip_bf16.h>
#include <math.h>

#define N_NODES 50000
#define E1 300000
#define EN 30000
#define ETOT 330000

typedef __hip_bfloat16 bf16;

__device__ __forceinline__ float b2f(bf16 x){ return __bfloat162float(x); }
__device__ __forceinline__ bf16 f2b(float x){ return __float2bfloat16(x); }

__device__ __forceinline__ float ldf(const void* p, long i, bool f32){
  return f32 ? ((const float*)p)[i] : b2f(((const bf16*)p)[i]);
}
__device__ __forceinline__ void stf(void* p, long i, float v, bool f32){
  if (f32) ((float*)p)[i] = v; else ((bf16*)p)[i] = f2b(v);
}
// packed 4-element store (16B fp32 / 8B bf16), elem must be multiple of 4
__device__ __forceinline__ void stv4(void* p, long elem, float a, float b,
                                     float c, float d, bool f32){
  if (f32){
    float4 t; t.x=a; t.y=b; t.z=c; t.w=d;
    *reinterpret_cast<float4*>((float*)p + elem) = t;
  } else {
    bf16 t[4] = {f2b(a), f2b(b), f2b(c), f2b(d)};
    *reinterpret_cast<uint2*>((bf16*)p + elem) = *reinterpret_cast<uint2*>(t);
  }
}

template<int NT>
__device__ __forceinline__ float block_sum(float v){
  __shared__ float sm[NT/64];
  #pragma unroll
  for (int o=32;o>0;o>>=1) v += __shfl_down(v,o);
  if ((threadIdx.x & 63)==0) sm[threadIdx.x>>6] = v;
  __syncthreads();
  float t = 0.f;
  #pragma unroll
  for (int w=0;w<NT/64;w++) t += sm[w];
  __syncthreads();
  return t;
}

// Detect input dtype: flag=0 -> bf16, flag=1 -> fp32
__global__ void k_detect(const void* __restrict__ emb, int* __restrict__ flag){
  const unsigned short* h = (const unsigned short*)emb;
  int sane = 0;
  for (int i=0;i<128;i++){
    unsigned e = (h[i]>>7)&0xFFu;
    if (e>=112u && e<=143u) sane++;
  }
  *flag = (sane >= 112) ? 0 : 1;
}

// ---- CSR build (by dst), shared by all 3 edge passes ----
__global__ void k_hist(const int* __restrict__ el, const int* __restrict__ eln,
                       int* __restrict__ cnt){
  int i = blockIdx.x*blockDim.x + threadIdx.x;
  if (i < ETOT){
    int dst = (i < E1) ? el[i] : eln[i - E1];
    atomicAdd(cnt + dst, 1);
  }
}

__global__ __launch_bounds__(1024) void k_scan(const int* __restrict__ cnt,
                                               int* __restrict__ rowp,
                                               int* __restrict__ cur){
  __shared__ int part[1024];
  int t = threadIdx.x;
  const int CH = (N_NODES + 1023)/1024;
  int base = t*CH;
  int s = 0;
  for (int i=0;i<CH;i++){ int n = base+i; if (n < N_NODES) s += cnt[n]; }
  part[t] = s;
  __syncthreads();
  for (int o=1;o<1024;o<<=1){
    int u = (t>=o) ? part[t-o] : 0;
    __syncthreads();
    part[t] += u;
    __syncthreads();
  }
  int off = part[t] - s;
  for (int i=0;i<CH;i++){
    int n = base+i;
    if (n < N_NODES){ rowp[n] = off; cur[n] = off; off += cnt[n]; }
  }
  if (t==0) rowp[N_NODES] = ETOT;
}

__global__ void k_fill(const int* __restrict__ el, const int* __restrict__ et,
                       const int* __restrict__ eln, const int* __restrict__ etn,
                       int* __restrict__ cur, int* __restrict__ esrc,
                       int* __restrict__ epak){
  int i = blockIdx.x*blockDim.x + threadIdx.x;
  if (i >= ETOT) return;
  int dst, src, pk;
  if (i < E1){
    dst = el[i]; src = el[E1 + i];
    pk = et[i];
  } else {
    int e = i - E1;
    dst = eln[e]; src = eln[EN + e];
    pk = etn[2*e] | (etn[2*e+1]<<9) | (1<<18);
  }
  int pos = atomicAdd(cur + dst, 1);
  esrc[pos] = src; epak[pos] = pk;
}

// ---- gather layer-1 (fused fin1): one wave per dst node, float2 lanes ----
__global__ __launch_bounds__(256) void k_gath1(
    const int* __restrict__ rowp, const int* __restrict__ esrc,
    const int* __restrict__ epak,
    const float* __restrict__ pd, const float* __restrict__ ps,
    const float* __restrict__ rp,
    const float* __restrict__ sd, const float* __restrict__ ss,
    const float* __restrict__ sr,
    float* __restrict__ x, int hoff){
  int w = threadIdx.x >> 6, lane = threadIdx.x & 63;
  int n = blockIdx.x*4 + w;
  if (n >= N_NODES) return;
  const float2* ps2 = (const float2*)ps;
  const float2* rp2 = (const float2*)rp;
  float2 acc; acc.x = 0.f; acc.y = 0.f;
  float rs = 0.f;
  float sdn = sd[n];
  int b = rowp[n], e = rowp[n+1];
  for (int i=b;i<e;i++){
    int src = esrc[i], pk = epak[i];
    int t0 = pk & 511, t1 = (pk>>9)&511, has2 = (pk>>18)&1;
    float srv = sr[t0] + (has2 ? sr[t1] : 0.f);
    float score = sdn + ss[src] + srv;
    float lr = score > 0.f ? score : 0.2f*score;
    float wgt = expf(-lr);
    rs += wgt;
    float2 v  = ps2[(long)src*64 + lane];
    float2 r1 = rp2[(long)t0*64 + lane];
    v.x += r1.x; v.y += r1.y;
    if (has2){ float2 r2v = rp2[(long)t1*64 + lane]; v.x += r2v.x; v.y += r2v.y; }
    acc.x += wgt*v.x; acc.y += wgt*v.y;
  }
  float denom = (rs == 0.f) ? 1e-12f : rs;
  float2 pdv = ((const float2*)pd)[(long)n*64 + lane];
  float hr0 = rs*pdv.x + acc.x, hr1 = rs*pdv.y + acc.y;
  float h0 = hr0/denom; h0 = h0 > 0.f ? h0 : (expf(h0) - 1.f);
  float h1 = hr1/denom; h1 = h1 > 0.f ? h1 : (expf(h1) - 1.f);
  float2 o; o.x = h0; o.y = h1;
  *reinterpret_cast<float2*>(x + (long)n*256 + hoff + lane*2) = o;
}

// ---- gather layer-2 (fused final epilogue): float4 lanes ----
__global__ __launch_bounds__(256) void k_gath2(
    const int* __restrict__ rowp, const int* __restrict__ esrc,
    const int* __restrict__ epak,
    const float* __restrict__ p2d, const float* __restrict__ ps,
    const float* __restrict__ rp,
    const float* __restrict__ sd, const float* __restrict__ ss,
    const float* __restrict__ sr,
    const float* __restrict__ eu, const float* __restrict__ mask,
    const int* __restrict__ flag, void* __restrict__ out){
  bool f32 = flag[0] != 0;
  int w = threadIdx.x >> 6, lane = threadIdx.x & 63;
  int n = blockIdx.x*4 + w;
  if (n >= N_NODES) return;
  const float4* ps4 = (const float4*)ps;
  const float4* rp4 = (const float4*)rp;
  float4 acc; acc.x=acc.y=acc.z=acc.w=0.f;
  float rs = 0.f;
  float sdn = sd[n];
  int b = rowp[n], e = rowp[n+1];
  for (int i=b;i<e;i++){
    int src = esrc[i], pk = epak[i];
    int t0 = pk & 511, t1 = (pk>>9)&511, has2 = (pk>>18)&1;
    float srv = sr[t0] + (has2 ? sr[t1] : 0.f);
    float score = sdn + ss[src] + srv;
    float lr = score > 0.f ? score : 0.2f*score;
    float wgt = expf(-lr);
    rs += wgt;
    float4 v  = ps4[(long)src*64 + lane];
    float4 r1 = rp4[(long)t0*64 + lane];
    v.x += r1.x; v.y += r1.y; v.z += r1.z; v.w += r1.w;
    if (has2){
      float4 r2v = rp4[(long)t1*64 + lane];
      v.x += r2v.x; v.y += r2v.y; v.z += r2v.z; v.w += r2v.w;
    }
    acc.x += wgt*v.x; acc.y += wgt*v.y; acc.z += wgt*v.z; acc.w += wgt*v.w;
  }
  float denom = (rs == 0.f) ? 1e-12f : rs;
  float mk = mask[n];
  float4 pdv = ((const float4*)p2d)[(long)n*64 + lane];
  float4 euv = ((const float4*)eu)[(long)n*64 + lane];
  float av[4] = {acc.x, acc.y, acc.z, acc.w};
  float pv[4] = {pdv.x, pdv.y, pdv.z, pdv.w};
  float ev[4] = {euv.x, euv.y, euv.z, euv.w};
  float val[4], xl[4];
  float n1 = 0.f, n2 = 0.f;
  #pragma unroll
  for (int m=0;m<4;m++){
    float hr = rs*pv[m] + av[m];
    float xo = hr/denom; xo = xo > 0.f ? xo : (expf(xo) - 1.f);
    float l  = hr > 0.f ? hr : (expf(hr) - 1.f);
    float v  = ev[m] + mk*xo;
    val[m] = v; xl[m] = l;
    n1 += v*v; n2 += l*l;
  }
  #pragma unroll
  for (int o=32;o>0;o>>=1){ n1 += __shfl_xor(n1,o); n2 += __shfl_xor(n2,o); }
  float i1 = 1.f/fmaxf(sqrtf(n1), 1e-12f);
  float i2 = 1.f/fmaxf(sqrtf(n2), 1e-12f);
  stv4(out, (long)n*256 + lane*4,
       val[0]*i1, val[1]*i1, val[2]*i1, val[3]*i1, f32);
  stv4(out, 12865536L + (long)n*256 + lane*4,
       xl[0]*i2, xl[1]*i2, xl[2]*i2, xl[3]*i2, f32);
}

// out_relation_1 = rel @ W  (fp32 copy to ws + dual-dtype output at element offset)
__global__ void k_rel2(const void* __restrict__ rel, const void* __restrict__ W,
                       const int* __restrict__ flag,
                       float* __restrict__ r2, void* __restrict__ out){
  bool f32 = flag[0] != 0;
  int t = blockIdx.x, j = threadIdx.x;   // 256 threads
  __shared__ float rs_[128];
  if (j < 128) rs_[j] = ldf(rel, (long)t*128 + j, f32);
  __syncthreads();
  float acc = 0.f;
  #pragma unroll 4
  for (int k=0;k<128;k++) acc += rs_[k]*ldf(W, (long)k*256 + j, f32);
  r2[(long)t*256+j] = acc;
  stf(out, 12800000L + (long)t*256 + j, acc, f32);
}

// Transpose weight block to fp32 [k][J]: dst[k*J+j] = src[bias + j*jstride + k]
__global__ void k_trF(const void* __restrict__ src, const int* __restrict__ flag,
                      long bias, long jstride, int J, float* __restrict__ dst){
  bool f32 = flag[0] != 0;
  int k = blockIdx.x, j = threadIdx.x;
  dst[(long)k*J + j] = ldf(src, bias + (long)j*jstride + k, f32);
}

// Convert-only (no transpose) to fp32: dst[i] = src[i]
__global__ void k_cvtF(const void* __restrict__ src, const int* __restrict__ flag,
                       int n, float* __restrict__ dst){
  bool f32 = flag[0] != 0;
  int i = blockIdx.x*blockDim.x + threadIdx.x;
  if (i < n) dst[i] = ldf(src, i, f32);
}

// Unified GEMM kernel: stage BM rows of X in LDS (optional fused l2norm),
// O1 = Xn @ WT1, optionally O2 = Xn @ WT2, optionally fused a2-scores.
// Inner loop: k-unroll-4 with float4 LDS broadcasts (ds_read_b128).
template<int NT, int K, int BM, int NORM, int DUAL, int SCORE, int XDUAL>
__global__ __launch_bounds__(NT) void k_gnp(
    const void* __restrict__ X, const int* __restrict__ flag, int N,
    const float* __restrict__ WT1, const float* __restrict__ WT2,
    const void* __restrict__ a2, long a2bias,
    float* __restrict__ O1, float* __restrict__ O2,
    float* __restrict__ s1, float* __restrict__ s2, int ldc){
  __shared__ __align__(16) float xs[BM][K];
  __shared__ float rsc[BM];
  const int NW = NT/64;
  __shared__ float red1[BM][NW];
  __shared__ float red2[BM][NW];
  int t = threadIdx.x;
  int n0 = blockIdx.x * BM;
  bool xf32 = XDUAL ? (flag[0] != 0) : true;

  for (int idx = t; idx < BM*K; idx += NT){
    int m = idx / K, k = idx - m*K;
    int n = n0 + m;
    xs[m][k] = (n < N) ? ldf(X, (long)n*K + k, xf32) : 0.f;
  }
  __syncthreads();

  if (NORM){
    const int NPR = NT / BM;
    int r = t / NPR, l = t - r*NPR;
    float ssq = 0.f;
    #pragma unroll
    for (int k = l; k < K; k += NPR){ float v = xs[r][k]; ssq += v*v; }
    #pragma unroll
    for (int o = NPR>>1; o > 0; o >>= 1) ssq += __shfl_xor(ssq, o);
    if (l == 0) rsc[r] = 1.f / fmaxf(sqrtf(ssq), 1e-12f);
    __syncthreads();
    for (int idx = t; idx < BM*K; idx += NT){
      int m = idx / K, k = idx - m*K;
      xs[m][k] *= rsc[m];
    }
    __syncthreads();
  }

  float a1c[BM], a2c[BM];
  #pragma unroll
  for (int m=0;m<BM;m++){ a1c[m]=0.f; a2c[m]=0.f; }
  const float4* xs4 = reinterpret_cast<const float4*>(&xs[0][0]);
  #pragma unroll 2
  for (int k0=0;k0<K;k0+=4){
    float w1a = WT1[(long)(k0+0)*NT + t];
    float w1b = WT1[(long)(k0+1)*NT + t];
    float w1c = WT1[(long)(k0+2)*NT + t];
    float w1d = WT1[(long)(k0+3)*NT + t];
    float w2a=0.f,w2b=0.f,w2c=0.f,w2d=0.f;
    if (DUAL){
      w2a = WT2[(long)(k0+0)*NT + t];
      w2b = WT2[(long)(k0+1)*NT + t];
      w2c = WT2[(long)(k0+2)*NT + t];
      w2d = WT2[(long)(k0+3)*NT + t];
    }
    #pragma unroll
    for (int m=0;m<BM;m++){
      float4 xv = xs4[(m*K + k0) >> 2];
      a1c[m] += xv.x*w1a + xv.y*w1b + xv.z*w1c + xv.w*w1d;
      if (DUAL) a2c[m] += xv.x*w2a + xv.y*w2b + xv.z*w2c + xv.w*w2d;
    }
  }

  #pragma unroll
  for (int m=0;m<BM;m++){
    int n = n0 + m;
    if (n < N){
      O1[(long)n*ldc + t] = a1c[m];
      if (DUAL) O2[(long)n*ldc + t] = a2c[m];
    }
  }

  if (SCORE){
    bool af32 = flag[0] != 0;
    float a2v = ldf(a2, a2bias + t, af32);
    int w = t >> 6, lane = t & 63;
    #pragma unroll
    for (int m=0;m<BM;m++){
      float v1 = a1c[m]*a2v;
      float v2 = DUAL ? a2c[m]*a2v : 0.f;
      #pragma unroll
      for (int o=32;o>0;o>>=1){ v1 += __shfl_down(v1,o); v2 += __shfl_down(v2,o); }
      if (lane==0){ red1[m][w]=v1; red2[m][w]=v2; }
    }
    __syncthreads();
    if (t < BM && n0 + t < N){
      float v1=0.f, v2=0.f;
      #pragma unroll
      for (int ww=0;ww<NW;ww++){ v1+=red1[t][ww]; v2+=red2[t][ww]; }
      s1[n0+t] = v1;
      if (DUAL) s2[n0+t] = v2;
    }
  }
}

__global__ void k_mask(const int* __restrict__ bi, float* __restrict__ mask){
  int i = blockIdx.x*blockDim.x + threadIdx.x;
  if (i < 4096) mask[bi[i*3 + 2]] = 1.f;
}

extern "C" void kernel_launch(void* const* d_in, const int* in_sizes, int n_in,
                              void* d_out, int out_size, void* d_ws, size_t ws_size,
                              hipStream_t stream) {
  const void* emb = d_in[0];
  const void* rel = d_in[1];
  const void* a1b = d_in[2];
  const void* a21 = d_in[3];
  const void* W   = d_in[4];
  const void* aout= d_in[5];
  const void* a2o = d_in[6];
  const void* We  = d_in[7];
  const int* bi   = (const int*)d_in[8];
  const int* el   = (const int*)d_in[9];
  const int* et   = (const int*)d_in[10];
  const int* eln  = (const int*)d_in[11];
  const int* etn  = (const int*)d_in[12];
  float* ws = (float*)d_ws;

  // Workspace layout (liveness-checked):
  //  [0,12.8M)      layer-1 pd|ps per head -> layer-2 p2d (live to k_gath2)
  //  [12.8M,19.2M)  CSR (cnt/cursor, rowp, esrc, epak)
  //  TW_=19.2M      transposed weights (L1: 6 blocks x16384; L2: 3 x65536)
  //  X_=25.6M       x fp32 (dead after layer-2 k_gnp) -> eu (live to k_gath2)
  //  P2S_=38.4M     layer-2 ps2 (live to k_gath2)
  //  RP1_           layer-1 rel proj (dead after gath1 h1) -> We fp32
  const size_t PD_=0, PS_=6400000;
  const size_t P2D_=0;
  const size_t CNT_=12800000, ROWP_=12860000, ESRC_=12920000, EPAK_=13260000;
  const size_t TW_=19200000;
  const size_t X_=25600000;        // x, later eu
  const size_t P2S_=38400000;
  const size_t SD_=51250000, SS_=51300000, S2D_=51350000,
               S2S_=51400000, MK_=51500000,
               RP1_=51550000, SR1_=51590000, R2_=51600000, RP2_=51670000,
               SR2_=51740000, FLAG_=51750000;
  int* flag = (int*)(ws + FLAG_);
  int* cnt  = (int*)(ws + CNT_);
  int* rowp = (int*)(ws + ROWP_);
  int* esrc = (int*)(ws + ESRC_);
  int* epak = (int*)(ws + EPAK_);

  k_detect<<<1,1,0,stream>>>(emb, flag);

  hipMemsetAsync(ws+MK_,  0, (size_t)50000*sizeof(float), stream);
  hipMemsetAsync(cnt,     0, (size_t)50000*sizeof(int), stream);

  // CSR build (once; shared by all 3 edge passes)
  k_hist<<<(ETOT+255)/256,256,0,stream>>>(el, eln, cnt);
  k_scan<<<1,1024,0,stream>>>(cnt, rowp, cnt);
  k_fill<<<(ETOT+255)/256,256,0,stream>>>(el, et, eln, etn, cnt, esrc, epak);

  // transpose the 6 layer-1 weight blocks to fp32 [k][128]
  k_trF<<<128,128,0,stream>>>(a1b, flag, 0L,          384L, 128, ws+TW_);          // h0 a_d
  k_trF<<<128,128,0,stream>>>(a1b, flag, 128L,        384L, 128, ws+TW_+16384);    // h0 a_s
  k_trF<<<128,128,0,stream>>>(a1b, flag, 49152L,      384L, 128, ws+TW_+32768);    // h1 a_d
  k_trF<<<128,128,0,stream>>>(a1b, flag, 49152L+128L, 384L, 128, ws+TW_+49152);    // h1 a_s
  k_trF<<<128,128,0,stream>>>(a1b, flag, 256L,        384L, 128, ws+TW_+65536);    // h0 a_r
  k_trF<<<128,128,0,stream>>>(a1b, flag, 49152L+256L, 384L, 128, ws+TW_+81920);    // h1 a_r

  // head 0: fused norm + dual projection + score; rel-proj via gnp; gather
  k_gnp<128,128,16,1,1,1,1><<<(N_NODES+15)/16,128,0,stream>>>(
      emb, flag, N_NODES, ws+TW_, ws+TW_+16384, a21, 0L,
      ws+PD_, ws+PS_, ws+SD_, ws+SS_, 128);
  k_gnp<128,128,16,0,0,1,1><<<16,128,0,stream>>>(
      rel, flag, 256, ws+TW_+65536, nullptr, a21, 0L,
      ws+RP1_, nullptr, ws+SR1_, nullptr, 128);
  k_gath1<<<(N_NODES+3)/4,256,0,stream>>>(rowp, esrc, epak,
      ws+PD_, ws+PS_, ws+RP1_, ws+SD_, ws+SS_, ws+SR1_, ws+X_, 0);

  // head 1
  k_gnp<128,128,16,1,1,1,1><<<(N_NODES+15)/16,128,0,stream>>>(
      emb, flag, N_NODES, ws+TW_+32768, ws+TW_+49152, a21, 128L,
      ws+PD_, ws+PS_, ws+SD_, ws+SS_, 128);
  k_gnp<128,128,16,0,0,1,1><<<16,128,0,stream>>>(
      rel, flag, 256, ws+TW_+81920, nullptr, a21, 128L,
      ws+RP1_, nullptr, ws+SR1_, nullptr, 128);
  k_gath1<<<(N_NODES+3)/4,256,0,stream>>>(rowp, esrc, epak,
      ws+PD_, ws+PS_, ws+RP1_, ws+SD_, ws+SS_, ws+SR1_, ws+X_, 128);

  k_rel2<<<256,256,0,stream>>>(rel, W, flag, ws+R2_, d_out);

  // layer-2 weight transposes (overwrites L1 TW; L1 done)
  k_trF<<<256,256,0,stream>>>(aout, flag, 0L,   768L, 256, ws+TW_);
  k_trF<<<256,256,0,stream>>>(aout, flag, 256L, 768L, 256, ws+TW_+65536);
  k_trF<<<256,256,0,stream>>>(aout, flag, 512L, 768L, 256, ws+TW_+131072);

  // layer-2 relation projection via gnp (coalesced)
  k_gnp<256,256,16,0,0,1,0><<<16,256,0,stream>>>(
      ws+R2_, flag, 256, ws+TW_+131072, nullptr, a2o, 0L,
      ws+RP2_, nullptr, ws+SR2_, nullptr, 256);

  // layer-2 node projection: fused dual projT + score
  k_gnp<256,256,16,0,1,1,0><<<(N_NODES+15)/16,256,0,stream>>>(
      ws+X_, flag, N_NODES, ws+TW_, ws+TW_+65536, a2o, 0L,
      ws+P2D_, ws+P2S_, ws+S2D_, ws+S2S_, 256);

  // x dead now. We fp32 -> RP1_ (rp1 dead); eu -> X_ (x dead)
  k_cvtF<<<128,256,0,stream>>>(We, flag, 32768, ws+RP1_);
  k_mask<<<16,256,0,stream>>>(bi, ws+MK_);
  k_gnp<256,128,16,1,0,0,1><<<(N_NODES+15)/16,256,0,stream>>>(
      emb, flag, N_NODES, ws+RP1_, nullptr, nullptr, 0L,
      ws+X_, nullptr, nullptr, nullptr, 256);

  // layer-2 gather with fused final epilogue -> d_out
  k_gath2<<<(N_NODES+3)/4,256,0,stream>>>(rowp, esrc, epak,
      ws+P2D_, ws+P2S_, ws+RP2_, ws+S2D_, ws+S2S_, ws+SR2_,
      ws+X_, ws+MK_, flag, d_out);
}